// Round 7
// baseline (152.902 us; speedup 1.0000x reference)
//
#include <hip/hip_runtime.h>
#include <math.h>

#define ALPHA_LEAKY 0.2f
#define EPS_F 1e-10f
#define NBMAX2 512        // max coarse buckets (128 nodes each; N <= 65536)
#define CHUNKS 128        // place chunks
#define EPBMAX 6400       // max edges per chunk (E <= 819200)
#define BCAPMAX 3072      // per-bucket csr slab (mean 2046 @ E=800K,nb2=391; +23 sigma)

typedef __attribute__((ext_vector_type(8))) short short8;   // 8 bf16 (4 VGPRs)
typedef __attribute__((ext_vector_type(4))) float f32x4;    // MFMA C/D frag

__device__ __forceinline__ unsigned short bf16_rne(float f) {
    unsigned u = __float_as_uint(f);
    u += 0x7FFFu + ((u >> 16) & 1u);
    return (unsigned short)(u >> 16);
}

// ---------------------------------------------------------------------------
// k_fused: gemm (blocks [0,GB)) || place (blocks [GB, GB+CHUNKS)) in ONE
// launch. The two phases share no data (gemm: X,W,a -> hb,s_src,s_tgt;
// place: ei -> st,histg), so no sync is needed -- this removes one launch
// gap AND overlaps MFMA-heavy gemm with LDS/memory-heavy place (R4 lesson:
// never grid-barrier on this chip; R6 lesson: atomic-free place3 needs no
// pre-zeroing, making it the legal merge partner).
// 1024 threads/block. Gemm: 16 waves, one 16-row stripe each, grid-stride.
// ---------------------------------------------------------------------------
__global__ __launch_bounds__(1024) void k_fused(
    const float* __restrict__ X, const float* __restrict__ W,
    const float* __restrict__ a, unsigned short* __restrict__ hb,
    float* __restrict__ s_src, float* __restrict__ s_tgt,
    const int* __restrict__ ei, int* __restrict__ histg,
    unsigned int* __restrict__ st,
    int n, int nstripes, int GB, int nb2, int E, int epb, int cap_cb) {
    // place-path LDS (allocated for all blocks; 32 KB total, still >=2
    // 16-wave blocks/CU against the 160 KB pool)
    __shared__ int hist[NBMAX2], lofs[NBMAX2], lcur[NBMAX2];
    __shared__ unsigned sorted[EPBMAX];
    __shared__ int wsum[8];

    const int t = threadIdx.x;
    const int lane = t & 63, w = t >> 6;

    if ((int)blockIdx.x < GB) {
        // ---------------- gemm path ----------------
        const int ml = lane & 15, g = lane >> 4;
        short8 bfr[4][4];
        #pragma unroll
        for (int nt = 0; nt < 4; ++nt)
            #pragma unroll
            for (int kt = 0; kt < 4; ++kt) {
                const float* wr = W + (nt * 16 + ml) * 128 + kt * 32 + g * 8;
                float4 w0 = *(const float4*)wr;
                float4 w1 = *(const float4*)(wr + 4);
                short8 bf;
                bf[0] = (short)bf16_rne(w0.x); bf[1] = (short)bf16_rne(w0.y);
                bf[2] = (short)bf16_rne(w0.z); bf[3] = (short)bf16_rne(w0.w);
                bf[4] = (short)bf16_rne(w1.x); bf[5] = (short)bf16_rne(w1.y);
                bf[6] = (short)bf16_rne(w1.z); bf[7] = (short)bf16_rne(w1.w);
                bfr[nt][kt] = bf;
            }
        float as[4], at[4];
        #pragma unroll
        for (int nt = 0; nt < 4; ++nt) {
            as[nt] = a[nt * 16 + ml];
            at[nt] = a[64 + nt * 16 + ml];
        }

        for (int stripe = blockIdx.x * 16 + w; stripe < nstripes;
             stripe += GB * 16) {
            const int row0 = stripe * 16;
            const int rrow = min(row0 + ml, n - 1);
            const float* xr = X + (size_t)rrow * 128;
            f32x4 acc[4] = {{0.f,0.f,0.f,0.f},{0.f,0.f,0.f,0.f},
                            {0.f,0.f,0.f,0.f},{0.f,0.f,0.f,0.f}};
            #pragma unroll
            for (int kt = 0; kt < 4; ++kt) {
                float4 x0 = *(const float4*)(xr + kt * 32 + g * 8);
                float4 x1 = *(const float4*)(xr + kt * 32 + g * 8 + 4);
                short8 af;
                af[0] = (short)bf16_rne(x0.x); af[1] = (short)bf16_rne(x0.y);
                af[2] = (short)bf16_rne(x0.z); af[3] = (short)bf16_rne(x0.w);
                af[4] = (short)bf16_rne(x1.x); af[5] = (short)bf16_rne(x1.y);
                af[6] = (short)bf16_rne(x1.z); af[7] = (short)bf16_rne(x1.w);
                #pragma unroll
                for (int nt = 0; nt < 4; ++nt)
                    acc[nt] = __builtin_amdgcn_mfma_f32_16x16x32_bf16(
                        af, bfr[nt][kt], acc[nt], 0, 0, 0);
            }
            #pragma unroll
            for (int reg = 0; reg < 4; ++reg) {
                int row = row0 + g * 4 + reg;
                float p = acc[0][reg] * as[0] + acc[1][reg] * as[1] +
                          acc[2][reg] * as[2] + acc[3][reg] * as[3];
                float q = acc[0][reg] * at[0] + acc[1][reg] * at[1] +
                          acc[2][reg] * at[2] + acc[3][reg] * at[3];
                #pragma unroll
                for (int off = 1; off < 16; off <<= 1) {
                    p += __shfl_xor(p, off, 64);
                    q += __shfl_xor(q, off, 64);
                }
                if (ml == 0 && row < n) { s_src[row] = p; s_tgt[row] = q; }
            }
            #pragma unroll
            for (int nt = 0; nt < 4; ++nt)
                #pragma unroll
                for (int reg = 0; reg < 4; ++reg) {
                    int row = row0 + g * 4 + reg;
                    if (row < n)
                        hb[(size_t)row * 64 + nt * 16 + ml] =
                            bf16_rne(acc[nt][reg]);
                }
        }
        return;
    }

    // ---------------- place path (R6 k_place3, atomic-free slabs) ----------
    const int c = blockIdx.x - GB;
    const int e0 = c * epb, e1 = min(e0 + epb, E);

    for (int k = t; k < NBMAX2; k += 1024) hist[k] = 0;
    __syncthreads();

    unsigned v[7];
    #pragma unroll
    for (int i = 0; i < 7; ++i) {
        int e = e0 + t + i * 1024;
        if (e < e1) {
            int s  = ei[e];
            int tt = ei[E + e];
            v[i] = (unsigned)s | ((unsigned)(tt & 127) << 16) |
                   ((unsigned)(tt >> 7) << 23);
            atomicAdd(&hist[tt >> 7], 1);
        }
    }
    __syncthreads();

    int hv = 0, pre = 0;
    if (t < NBMAX2) {
        hv = hist[t];
        pre = hv;
        #pragma unroll
        for (int off = 1; off < 64; off <<= 1) {
            int x = __shfl_up(pre, off, 64);
            if (lane >= off) pre += x;
        }
        if (lane == 63) wsum[w] = pre;
    }
    __syncthreads();
    if (t < NBMAX2) {
        int wb = 0;
        #pragma unroll
        for (int k = 0; k < 8; ++k) if (k < w) wb += wsum[k];
        int ex = wb + pre - hv;
        lofs[t] = ex;
        lcur[t] = ex;
    }
    __syncthreads();

    #pragma unroll
    for (int i = 0; i < 7; ++i) {
        int e = e0 + t + i * 1024;
        if (e < e1) {
            unsigned ent = v[i];
            int b = ent >> 23;
            int slot = atomicAdd(&lcur[b], 1);
            sorted[slot] = ent;
        }
    }
    __syncthreads();

    const int cnt = e1 - e0;
    for (int i = t; i < cnt; i += 1024) {
        unsigned ent = sorted[i];
        int b = ent >> 23;
        int ofs = i - lofs[b];
        if (ofs < cap_cb)
            st[((size_t)c * nb2 + b) * cap_cb + ofs] = ent & 0x7FFFFFu;
    }
    for (int k = t; k < nb2; k += 1024)
        histg[(size_t)c * nb2 + k] = min(hist[k], cap_cb);
}

// ---------------------------------------------------------------------------
// k_local2: one block per 128-node bucket (unchanged from R6).
// ---------------------------------------------------------------------------
__global__ __launch_bounds__(256) void k_local2(
    const unsigned int* __restrict__ st, const int* __restrict__ histg,
    int* __restrict__ base, int* __restrict__ deg, int* __restrict__ csr_g,
    int nb2, int cap_cb, int n) {
    __shared__ int cnts[CHUNKS], cofs[CHUNKS];
    __shared__ int hist[128], lofs[128];
    __shared__ unsigned raw[BCAPMAX];
    __shared__ int lsorted[BCAPMAX];
    __shared__ int wsum[4];
    __shared__ int sh_tot;
    const int b = blockIdx.x;
    const int t = threadIdx.x, lane = t & 63, w = t >> 6;

    if (t < CHUNKS) cnts[t] = histg[(size_t)t * nb2 + b];
    __syncthreads();

    int hv = 0, pre = 0;
    if (t < CHUNKS) {
        hv = cnts[t];
        pre = hv;
        #pragma unroll
        for (int off = 1; off < 64; off <<= 1) {
            int x = __shfl_up(pre, off, 64);
            if (lane >= off) pre += x;
        }
        if (lane == 63) wsum[w] = pre;
    }
    __syncthreads();
    if (t < CHUNKS) {
        int wb = (w >= 1) ? wsum[0] : 0;
        cofs[t] = wb + pre - hv;
        if (t == CHUNKS - 1) sh_tot = min(wb + pre, BCAPMAX);
    }
    __syncthreads();

    for (int c = w; c < CHUNKS; c += 4) {
        int cc = cnts[c], co = cofs[c];
        size_t cell = ((size_t)c * nb2 + b) * cap_cb;
        for (int i = lane; i < cc; i += 64)
            if (co + i < BCAPMAX) raw[co + i] = st[cell + i];
    }
    if (t < 128) hist[t] = 0;
    __syncthreads();

    const int tot = sh_tot;
    for (int i = t; i < tot; i += 256)
        atomicAdd(&hist[(raw[i] >> 16) & 127], 1);
    __syncthreads();

    int nh = 0, npre = 0;
    if (t < 128) {
        nh = hist[t];
        npre = nh;
        #pragma unroll
        for (int off = 1; off < 64; off <<= 1) {
            int x = __shfl_up(npre, off, 64);
            if (lane >= off) npre += x;
        }
        if (lane == 63) wsum[w] = npre;
    }
    __syncthreads();
    if (t < 128) {
        int wb = (w >= 1) ? wsum[0] : 0;
        int ex = wb + npre - nh;
        lofs[t] = ex;
        int node = (b << 7) + t;
        if (node < n) { base[node] = b * BCAPMAX + ex; deg[node] = nh; }
    }
    __syncthreads();
    if (t < 128) hist[t] = lofs[t];
    __syncthreads();
    for (int i = t; i < tot; i += 256) {
        unsigned e = raw[i];
        int slot = atomicAdd(&hist[(e >> 16) & 127], 1);
        lsorted[slot] = (int)(e & 0xFFFFu);
    }
    __syncthreads();
    const int bb = b * BCAPMAX;
    for (int i = t; i < tot; i += 256) csr_g[bb + i] = lsorted[i];
}

// ---------------------------------------------------------------------------
// k_node: per-node softmax + aggregation + ELU (unchanged; one wave per
// node, full 12.5K-block grid -- R3 lesson).
// ---------------------------------------------------------------------------
__device__ __forceinline__ void accum8(float acc[8], uint4 hv, float w) {
    unsigned u[4] = {hv.x, hv.y, hv.z, hv.w};
    #pragma unroll
    for (int i = 0; i < 4; ++i) {
        float lo = __uint_as_float(u[i] << 16);
        float hi = __uint_as_float(u[i] & 0xFFFF0000u);
        acc[2 * i]     = fmaf(w, lo, acc[2 * i]);
        acc[2 * i + 1] = fmaf(w, hi, acc[2 * i + 1]);
    }
}

__global__ __launch_bounds__(256) void k_node(
    const int* __restrict__ base, const int* __restrict__ deg,
    const int* __restrict__ csr_src, const float* __restrict__ s_src,
    const float* __restrict__ s_tgt, const unsigned short* __restrict__ hb,
    float* __restrict__ out, int n) {
    const int lane = threadIdx.x & 63;
    const int node = blockIdx.x * 4 + (threadIdx.x >> 6);
    if (node >= n) return;
    const int b = base[node];
    const int d = deg[node];
    const float st = s_tgt[node];
    const int g = lane >> 3, r = lane & 7;
    float acc[8] = {0.f, 0.f, 0.f, 0.f, 0.f, 0.f, 0.f, 0.f};

    if (d <= 64) {
        int src_l = 0; float w_l = 0.f, v = -INFINITY;
        if (lane < d) {
            src_l = csr_src[b + lane];
            float x = s_src[src_l] + st;
            v = (x > 0.f) ? x : ALPHA_LEAKY * x;
        }
        float m = v;
        #pragma unroll
        for (int off = 32; off > 0; off >>= 1) m = fmaxf(m, __shfl_xor(m, off, 64));
        float ex = (lane < d) ? expf(v - m) : 0.f;
        float sum = ex;
        #pragma unroll
        for (int off = 32; off > 0; off >>= 1) sum += __shfl_xor(sum, off, 64);
        w_l = ex * (1.f / (sum + EPS_F));
        for (int k = 0; k < d; k += 8) {
            int ke = k + g;
            int s   = __shfl(src_l, ke, 64);
            float w = __shfl(w_l,  ke, 64);
            uint4 hv = ((const uint4*)(hb + (size_t)s * 64))[r];
            accum8(acc, hv, w);
        }
    } else {
        float m = -INFINITY;
        for (int c = lane; c < d; c += 64) {
            float x = s_src[csr_src[b + c]] + st;
            x = (x > 0.f) ? x : ALPHA_LEAKY * x;
            m = fmaxf(m, x);
        }
        #pragma unroll
        for (int off = 32; off > 0; off >>= 1) m = fmaxf(m, __shfl_xor(m, off, 64));
        float sum = 0.f;
        for (int c = lane; c < d; c += 64) {
            float x = s_src[csr_src[b + c]] + st;
            x = (x > 0.f) ? x : ALPHA_LEAKY * x;
            sum += expf(x - m);
        }
        #pragma unroll
        for (int off = 32; off > 0; off >>= 1) sum += __shfl_xor(sum, off, 64);
        float inv = 1.f / (sum + EPS_F);
        for (int c0 = 0; c0 < d; c0 += 64) {
            int j = c0 + lane;
            int src_l = 0; float w_l = 0.f;
            if (j < d) {
                src_l = csr_src[b + j];
                float x = s_src[src_l] + st;
                x = (x > 0.f) ? x : ALPHA_LEAKY * x;
                w_l = expf(x - m) * inv;
            }
            int lim = min(64, d - c0);
            for (int k = 0; k < lim; k += 8) {
                int ke = k + g;
                int s   = __shfl(src_l, ke, 64);
                float w = __shfl(w_l,  ke, 64);
                uint4 hv = ((const uint4*)(hb + (size_t)s * 64))[r];
                accum8(acc, hv, w);
            }
        }
    }

    #pragma unroll
    for (int off = 8; off <= 32; off <<= 1) {
        #pragma unroll
        for (int j = 0; j < 8; ++j) acc[j] += __shfl_xor(acc[j], off, 64);
    }
    if (g == 0) {
        float4 o0, o1;
        o0.x = acc[0] > 0.f ? acc[0] : expf(acc[0]) - 1.f;
        o0.y = acc[1] > 0.f ? acc[1] : expf(acc[1]) - 1.f;
        o0.z = acc[2] > 0.f ? acc[2] : expf(acc[2]) - 1.f;
        o0.w = acc[3] > 0.f ? acc[3] : expf(acc[3]) - 1.f;
        o1.x = acc[4] > 0.f ? acc[4] : expf(acc[4]) - 1.f;
        o1.y = acc[5] > 0.f ? acc[5] : expf(acc[5]) - 1.f;
        o1.z = acc[6] > 0.f ? acc[6] : expf(acc[6]) - 1.f;
        o1.w = acc[7] > 0.f ? acc[7] : expf(acc[7]) - 1.f;
        float4* o4 = (float4*)out + (size_t)node * 16;
        o4[r * 2]     = o0;
        o4[r * 2 + 1] = o1;
    }
}

extern "C" void kernel_launch(void* const* d_in, const int* in_sizes, int n_in,
                              void* d_out, int out_size, void* d_ws, size_t ws_size,
                              hipStream_t stream) {
    const float* X  = (const float*)d_in[0];   // [N,128]
    const int*   ei = (const int*)d_in[1];     // [2,E]
    const float* W  = (const float*)d_in[2];   // [64,128]
    const float* a  = (const float*)d_in[3];   // [1,128]
    float* out = (float*)d_out;                // [N,64]

    const int N = in_sizes[0] / 128;
    const int E = in_sizes[1] / 2;
    const int nb2 = (N + 127) >> 7;            // coarse buckets of 128 nodes
    const int nstripes = (N + 15) / 16;
    const int GB = (nstripes + 15) / 16;       // gemm blocks (16 stripes each)
    const int epb = (E + CHUNKS - 1) / CHUNKS; // <= EPBMAX for E <= 819200

    // per-cell capacity: lam + 6*sqrt(lam) + 17, rounded up to 8
    const int lam = (epb + nb2 - 1) / nb2;
    int cap_cb = lam + 6 * (int)ceil(sqrt((double)lam)) + 17;
    cap_cb = (cap_cb + 7) & ~7;

    char* p = (char*)d_ws;
    unsigned short* hb = (unsigned short*)p; p += (size_t)N * 64 * sizeof(unsigned short);
    float* s_src  = (float*)p;  p += (size_t)N * sizeof(float);
    float* s_tgt  = (float*)p;  p += (size_t)N * sizeof(float);
    int*   deg    = (int*)p;    p += (size_t)N * sizeof(int);
    int*   base   = (int*)p;    p += (size_t)N * sizeof(int);
    int*   histg  = (int*)p;    p += (size_t)CHUNKS * nb2 * sizeof(int);
    int*   csr_g  = (int*)p;    p += (size_t)nb2 * BCAPMAX * sizeof(int);
    unsigned int* st = (unsigned int*)p;       // CHUNKS * nb2 * cap_cb * 4 B

    k_fused <<<GB + CHUNKS, 1024, 0, stream>>>(X, W, a, hb, s_src, s_tgt,
                                               ei, histg, st, N, nstripes,
                                               GB, nb2, E, epb, cap_cb);
    k_local2<<<nb2, 256, 0, stream>>>(st, histg, base, deg, csr_g, nb2, cap_cb, N);
    k_node  <<<(N + 3) / 4, 256, 0, stream>>>(base, deg, csr_g, s_src, s_tgt,
                                              hb, out, N);
}

// Round 9
// 142.473 us; speedup vs baseline: 1.0732x; 1.0732x over previous
//
#include <hip/hip_runtime.h>
#include <hip/hip_bf16.h>
#include <math.h>

#define ALPHA_LEAKY 0.2f
#define EPS_F 1e-10f
#define NBMAX 1024   // max buckets (N <= 65536; src fits 16 bits in packed entry)
#define CAP 2048     // fixed bucket region capacity (mean 1023, sigma 32)
#define PLACE_BLOCKS 256
#define EPBMAX 3200  // max edges per place chunk (E <= 819200)

typedef __attribute__((ext_vector_type(8))) short short8;   // 8 bf16 (4 VGPRs)
typedef __attribute__((ext_vector_type(4))) float f32x4;    // MFMA C/D frag

__device__ __forceinline__ unsigned short bf16_rne(float f) {
    unsigned u = __float_as_uint(f);
    u += 0x7FFFu + ((u >> 16) & 1u);
    return (unsigned short)(u >> 16);
}

// f32 -> bf16 via the HIP intrinsic (RNE). On ROCm7/gfx950 __hip_bfloat16
// wraps native __bf16; the backend lowers the fptrunc to hardware cvt and
// can fuse adjacent pairs into v_cvt_pk_bf16_f32 (T12: let the compiler
// emit cvt -- don't hand-write asm). R8 lesson: __floats2bfloat162_rn is
// CUDA-only spelling; __float2bfloat16 is the portable one.
__device__ __forceinline__ unsigned short f2bf(float f) {
    union { __hip_bfloat16 h; unsigned short u; } cv;
    cv.h = __float2bfloat16(f);
    return cv.u;
}
__device__ __forceinline__ short8 pack8(float4 x0, float4 x1) {
    union { unsigned u[4]; short8 s; } r;
    r.u[0] = (unsigned)f2bf(x0.x) | ((unsigned)f2bf(x0.y) << 16);
    r.u[1] = (unsigned)f2bf(x0.z) | ((unsigned)f2bf(x0.w) << 16);
    r.u[2] = (unsigned)f2bf(x1.x) | ((unsigned)f2bf(x1.y) << 16);
    r.u[3] = (unsigned)f2bf(x1.z) | ((unsigned)f2bf(x1.w) << 16);
    return r.s;
}

// ---------------------------------------------------------------------------
// k_gemm: MFMA GEMM + fused scores (R5 structure; A/W-frag conversion via
// compiler cvt). Block 0 zeroes the bucket cursors for k_place2.
// C/D map: col = lane&15 (ml), row = (lane>>4)*4 + reg.
// ---------------------------------------------------------------------------
__global__ __launch_bounds__(256) void k_gemm(
    const float* __restrict__ X, const float* __restrict__ W,
    const float* __restrict__ a, unsigned short* __restrict__ hb,
    float* __restrict__ s_src, float* __restrict__ s_tgt,
    int* __restrict__ cur, int nb, int n, int nstripes) {
    if (blockIdx.x == 0)
        for (int k = threadIdx.x; k < nb; k += 256) cur[k] = 0;

    const int lane = threadIdx.x & 63;
    const int ml = lane & 15, g = lane >> 4;

    short8 bfr[4][4];
    #pragma unroll
    for (int nt = 0; nt < 4; ++nt)
        #pragma unroll
        for (int kt = 0; kt < 4; ++kt) {
            const float* wr = W + (nt * 16 + ml) * 128 + kt * 32 + g * 8;
            bfr[nt][kt] = pack8(*(const float4*)wr, *(const float4*)(wr + 4));
        }
    float as[4], at[4];
    #pragma unroll
    for (int nt = 0; nt < 4; ++nt) {
        as[nt] = a[nt * 16 + ml];
        at[nt] = a[64 + nt * 16 + ml];
    }

    for (int stripe = blockIdx.x * 4 + (threadIdx.x >> 6); stripe < nstripes;
         stripe += gridDim.x * 4) {
        const int row0 = stripe * 16;
        const int rrow = min(row0 + ml, n - 1);
        const float* xr = X + (size_t)rrow * 128;
        f32x4 acc[4] = {{0.f,0.f,0.f,0.f},{0.f,0.f,0.f,0.f},
                        {0.f,0.f,0.f,0.f},{0.f,0.f,0.f,0.f}};
        #pragma unroll
        for (int kt = 0; kt < 4; ++kt) {
            float4 x0 = *(const float4*)(xr + kt * 32 + g * 8);
            float4 x1 = *(const float4*)(xr + kt * 32 + g * 8 + 4);
            short8 af = pack8(x0, x1);
            #pragma unroll
            for (int nt = 0; nt < 4; ++nt)
                acc[nt] = __builtin_amdgcn_mfma_f32_16x16x32_bf16(
                    af, bfr[nt][kt], acc[nt], 0, 0, 0);
        }
        #pragma unroll
        for (int reg = 0; reg < 4; ++reg) {
            int row = row0 + g * 4 + reg;
            float p = acc[0][reg] * as[0] + acc[1][reg] * as[1] +
                      acc[2][reg] * as[2] + acc[3][reg] * as[3];
            float q = acc[0][reg] * at[0] + acc[1][reg] * at[1] +
                      acc[2][reg] * at[2] + acc[3][reg] * at[3];
            #pragma unroll
            for (int off = 1; off < 16; off <<= 1) {
                p += __shfl_xor(p, off, 64);
                q += __shfl_xor(q, off, 64);
            }
            if (ml == 0 && row < n) { s_src[row] = p; s_tgt[row] = q; }
        }
        #pragma unroll
        for (int nt = 0; nt < 4; ++nt)
            #pragma unroll
            for (int reg = 0; reg < 4; ++reg) {
                int row = row0 + g * 4 + reg;
                if (row < n)
                    hb[(size_t)row * 64 + nt * 16 + ml] = bf16_rne(acc[nt][reg]);
            }
    }
}

// ---------------------------------------------------------------------------
// k_place2: hist + alloc + place in ONE kernel (R5 proven). Bucket regions
// are fixed-capacity slabs st[b*CAP..]; each (chunk,bucket) segment reserved
// with one atomicAdd on cur[b]. Chunk edges LDS-sorted by bucket so the
// copy-out is sequential. 256 chunks x 1024 threads.
// ---------------------------------------------------------------------------
__global__ __launch_bounds__(1024) void k_place2(
    const int* __restrict__ ei, int* __restrict__ cur,
    unsigned int* __restrict__ st, int nb, int E, int epb) {
    __shared__ int hist[NBMAX];
    __shared__ int lofs[NBMAX];
    __shared__ int gbase[NBMAX];
    __shared__ int lcur[NBMAX];
    __shared__ unsigned sorted[EPBMAX];
    __shared__ int wsum[16];
    const int t = threadIdx.x;
    const int lane = t & 63, w = t >> 6;
    const int e0 = blockIdx.x * epb, e1 = min(e0 + epb, E);
    const int cnt = e1 - e0;

    for (int k = t; k < NBMAX; k += 1024) hist[k] = 0;
    __syncthreads();

    unsigned v[4]; int nv = 0;
    for (int e = e0 + t; e < e1; e += 1024) {
        int s  = ei[e];
        int tt = ei[E + e];
        unsigned ent = (unsigned)s | ((unsigned)(tt & 63) << 16) |
                       ((unsigned)(tt >> 6) << 22);
        v[nv++] = ent;
        atomicAdd(&hist[tt >> 6], 1);
    }
    __syncthreads();

    {
        int hv = (t < nb) ? hist[t] : 0;
        int pre = hv;
        #pragma unroll
        for (int off = 1; off < 64; off <<= 1) {
            int x = __shfl_up(pre, off, 64);
            if (lane >= off) pre += x;
        }
        if (lane == 63) wsum[w] = pre;
        __syncthreads();
        int wb = 0;
        for (int k = 0; k < 16; ++k) if (k < w) wb += wsum[k];
        if (t < nb) {
            int ex = wb + pre - hv;
            lofs[t] = ex;
            lcur[t] = ex;
            if (hv > 0) gbase[t] = atomicAdd(&cur[t], hv);
        }
    }
    __syncthreads();

    for (int i = 0; i < nv; ++i) {
        unsigned ent = v[i];
        int b = ent >> 22;
        int slot = atomicAdd(&lcur[b], 1);
        sorted[slot] = ent;
    }
    __syncthreads();

    for (int i = t; i < cnt; i += 1024) {
        unsigned ent = sorted[i];
        int b = ent >> 22;
        int addr = b * CAP + gbase[b] + (i - lofs[b]);
        st[addr] = ent & 0x3FFFFFu;
    }
}

// ---------------------------------------------------------------------------
// k_local: per-bucket sort by node (R5 proven). LDS-staged hist -> scan ->
// LDS scatter, coalesced csr copy-out.
// ---------------------------------------------------------------------------
__global__ __launch_bounds__(256) void k_local(
    const unsigned int* __restrict__ st, const int* __restrict__ cur,
    int* __restrict__ base, int* __restrict__ deg, int* __restrict__ csr_g,
    int n) {
    __shared__ int hist[64], lofs[64];
    __shared__ int lsorted[CAP];
    const int b = blockIdx.x;
    const int s0 = b * CAP;
    const int t = threadIdx.x;
    const int cnt = min(cur[b], CAP);
    if (t < 64) hist[t] = 0;
    __syncthreads();

    unsigned v[CAP / 256]; int nv = 0;
    for (int i = t; i < cnt; i += 256) {
        unsigned e = st[s0 + i];
        v[nv++] = e;
        atomicAdd(&hist[e >> 16], 1);
    }
    __syncthreads();
    if (t < 64) {
        int hv = hist[t];
        int pre = hv;
        #pragma unroll
        for (int off = 1; off < 64; off <<= 1) {
            int x = __shfl_up(pre, off, 64);
            if (t >= off) pre += x;
        }
        int ex = pre - hv;
        lofs[t] = ex;
        int node = (b << 6) + t;
        if (node < n) { base[node] = s0 + ex; deg[node] = hv; }
    }
    __syncthreads();
    if (t < 64) hist[t] = lofs[t];          // reuse as cursors
    __syncthreads();
    for (int i = 0; i < nv; ++i) {
        unsigned e = v[i];
        int slot = atomicAdd(&hist[e >> 16], 1);
        lsorted[slot] = (int)(e & 0xFFFFu);
    }
    __syncthreads();
    for (int i = t; i < cnt; i += 256) csr_g[s0 + i] = lsorted[i];
}

// ---------------------------------------------------------------------------
// k_node: per-node softmax + aggregation + ELU (R5 proven; one wave per
// node, full 12.5K-block grid).
// ---------------------------------------------------------------------------
__device__ __forceinline__ void accum8(float acc[8], uint4 hv, float w) {
    unsigned u[4] = {hv.x, hv.y, hv.z, hv.w};
    #pragma unroll
    for (int i = 0; i < 4; ++i) {
        float lo = __uint_as_float(u[i] << 16);
        float hi = __uint_as_float(u[i] & 0xFFFF0000u);
        acc[2 * i]     = fmaf(w, lo, acc[2 * i]);
        acc[2 * i + 1] = fmaf(w, hi, acc[2 * i + 1]);
    }
}

__global__ __launch_bounds__(256) void k_node(
    const int* __restrict__ base, const int* __restrict__ deg,
    const int* __restrict__ csr_src, const float* __restrict__ s_src,
    const float* __restrict__ s_tgt, const unsigned short* __restrict__ hb,
    float* __restrict__ out, int n) {
    const int lane = threadIdx.x & 63;
    const int node = blockIdx.x * 4 + (threadIdx.x >> 6);
    if (node >= n) return;
    const int b = base[node];
    const int d = deg[node];
    const float st = s_tgt[node];
    const int g = lane >> 3, r = lane & 7;
    float acc[8] = {0.f, 0.f, 0.f, 0.f, 0.f, 0.f, 0.f, 0.f};

    if (d <= 64) {
        int src_l = 0; float w_l = 0.f, v = -INFINITY;
        if (lane < d) {
            src_l = csr_src[b + lane];
            float x = s_src[src_l] + st;
            v = (x > 0.f) ? x : ALPHA_LEAKY * x;
        }
        float m = v;
        #pragma unroll
        for (int off = 32; off > 0; off >>= 1) m = fmaxf(m, __shfl_xor(m, off, 64));
        float ex = (lane < d) ? expf(v - m) : 0.f;
        float sum = ex;
        #pragma unroll
        for (int off = 32; off > 0; off >>= 1) sum += __shfl_xor(sum, off, 64);
        w_l = ex * (1.f / (sum + EPS_F));
        for (int k = 0; k < d; k += 8) {
            int ke = k + g;
            int s   = __shfl(src_l, ke, 64);
            float w = __shfl(w_l,  ke, 64);
            uint4 hv = ((const uint4*)(hb + (size_t)s * 64))[r];
            accum8(acc, hv, w);
        }
    } else {
        float m = -INFINITY;
        for (int c = lane; c < d; c += 64) {
            float x = s_src[csr_src[b + c]] + st;
            x = (x > 0.f) ? x : ALPHA_LEAKY * x;
            m = fmaxf(m, x);
        }
        #pragma unroll
        for (int off = 32; off > 0; off >>= 1) m = fmaxf(m, __shfl_xor(m, off, 64));
        float sum = 0.f;
        for (int c = lane; c < d; c += 64) {
            float x = s_src[csr_src[b + c]] + st;
            x = (x > 0.f) ? x : ALPHA_LEAKY * x;
            sum += expf(x - m);
        }
        #pragma unroll
        for (int off = 32; off > 0; off >>= 1) sum += __shfl_xor(sum, off, 64);
        float inv = 1.f / (sum + EPS_F);
        for (int c0 = 0; c0 < d; c0 += 64) {
            int j = c0 + lane;
            int src_l = 0; float w_l = 0.f;
            if (j < d) {
                src_l = csr_src[b + j];
                float x = s_src[src_l] + st;
                x = (x > 0.f) ? x : ALPHA_LEAKY * x;
                w_l = expf(x - m) * inv;
            }
            int lim = min(64, d - c0);
            for (int k = 0; k < lim; k += 8) {
                int ke = k + g;
                int s   = __shfl(src_l, ke, 64);
                float w = __shfl(w_l,  ke, 64);
                uint4 hv = ((const uint4*)(hb + (size_t)s * 64))[r];
                accum8(acc, hv, w);
            }
        }
    }

    #pragma unroll
    for (int off = 8; off <= 32; off <<= 1) {
        #pragma unroll
        for (int j = 0; j < 8; ++j) acc[j] += __shfl_xor(acc[j], off, 64);
    }
    if (g == 0) {
        float4 o0, o1;
        o0.x = acc[0] > 0.f ? acc[0] : expf(acc[0]) - 1.f;
        o0.y = acc[1] > 0.f ? acc[1] : expf(acc[1]) - 1.f;
        o0.z = acc[2] > 0.f ? acc[2] : expf(acc[2]) - 1.f;
        o0.w = acc[3] > 0.f ? acc[3] : expf(acc[3]) - 1.f;
        o1.x = acc[4] > 0.f ? acc[4] : expf(acc[4]) - 1.f;
        o1.y = acc[5] > 0.f ? acc[5] : expf(acc[5]) - 1.f;
        o1.z = acc[6] > 0.f ? acc[6] : expf(acc[6]) - 1.f;
        o1.w = acc[7] > 0.f ? acc[7] : expf(acc[7]) - 1.f;
        float4* o4 = (float4*)out + (size_t)node * 16;
        o4[r * 2]     = o0;
        o4[r * 2 + 1] = o1;
    }
}

extern "C" void kernel_launch(void* const* d_in, const int* in_sizes, int n_in,
                              void* d_out, int out_size, void* d_ws, size_t ws_size,
                              hipStream_t stream) {
    const float* X  = (const float*)d_in[0];   // [N,128]
    const int*   ei = (const int*)d_in[1];     // [2,E]
    const float* W  = (const float*)d_in[2];   // [64,128]
    const float* a  = (const float*)d_in[3];   // [1,128]
    float* out = (float*)d_out;                // [N,64]

    const int N = in_sizes[0] / 128;
    const int E = in_sizes[1] / 2;
    const int nb = (N + 63) >> 6;              // buckets of 64 nodes (<=1024)
    const int nstripes = (N + 15) / 16;
    const int Rg = (nstripes + 3) / 4;         // gemm grid
    const int epb = (E + PLACE_BLOCKS - 1) / PLACE_BLOCKS;

    char* p = (char*)d_ws;
    unsigned short* hb = (unsigned short*)p; p += (size_t)N * 64 * sizeof(unsigned short);
    float* s_src  = (float*)p;  p += (size_t)N * sizeof(float);
    float* s_tgt  = (float*)p;  p += (size_t)N * sizeof(float);
    int*   deg    = (int*)p;    p += (size_t)N * sizeof(int);
    int*   base   = (int*)p;    p += (size_t)N * sizeof(int);
    int*   cur    = (int*)p;    p += (size_t)NBMAX * sizeof(int);
    unsigned int* st = (unsigned int*)p; p += (size_t)nb * CAP * sizeof(unsigned int);
    int*   csr_g  = (int*)p;

    k_gemm  <<<Rg, 256, 0, stream>>>(X, W, a, hb, s_src, s_tgt, cur, nb, N, nstripes);
    k_place2<<<PLACE_BLOCKS, 1024, 0, stream>>>(ei, cur, st, nb, E, epb);
    k_local <<<nb, 256, 0, stream>>>(st, cur, base, deg, csr_g, N);
    k_node  <<<(N + 3) / 4, 256, 0, stream>>>(base, deg, csr_g, s_src, s_tgt,
                                              hb, out, N);
}

// Round 11
// 132.541 us; speedup vs baseline: 1.1536x; 1.0749x over previous
//
#include <hip/hip_runtime.h>
#include <math.h>

#define ALPHA_LEAKY 0.2f
#define EPS_F 1e-10f
#define NBMAX 1024   // max buckets (N <= 65536; src fits 16 bits in packed entry)
#define CAP 2048     // fixed bucket region capacity (mean 1023, sigma 32)
#define PLACE_BLOCKS 256
#define EPBMAX 3200  // max edges per place chunk (E <= 819200)

typedef __attribute__((ext_vector_type(8))) short short8;   // 8 bf16 (4 VGPRs)
typedef __attribute__((ext_vector_type(4))) float f32x4;    // MFMA C/D frag

__device__ __forceinline__ unsigned short bf16_rne(float f) {
    unsigned u = __float_as_uint(f);
    u += 0x7FFFu + ((u >> 16) & 1u);
    return (unsigned short)(u >> 16);
}

// ---------------------------------------------------------------------------
// k_gemm: MFMA GEMM + fused scores (R5-exact; R9's cvt repack was neutral ->
// reverted for clean attribution). Block 0 zeroes bucket cursors for place2.
// C/D map: col = lane&15 (ml), row = (lane>>4)*4 + reg.
// ---------------------------------------------------------------------------
__global__ __launch_bounds__(256) void k_gemm(
    const float* __restrict__ X, const float* __restrict__ W,
    const float* __restrict__ a, unsigned short* __restrict__ hb,
    float* __restrict__ s_src, float* __restrict__ s_tgt,
    int* __restrict__ cur, int nb, int n, int nstripes) {
    if (blockIdx.x == 0)
        for (int k = threadIdx.x; k < nb; k += 256) cur[k] = 0;

    const int lane = threadIdx.x & 63;
    const int ml = lane & 15, g = lane >> 4;

    short8 bfr[4][4];
    #pragma unroll
    for (int nt = 0; nt < 4; ++nt)
        #pragma unroll
        for (int kt = 0; kt < 4; ++kt) {
            const float* wr = W + (nt * 16 + ml) * 128 + kt * 32 + g * 8;
            float4 w0 = *(const float4*)wr;
            float4 w1 = *(const float4*)(wr + 4);
            short8 bf;
            bf[0] = (short)bf16_rne(w0.x); bf[1] = (short)bf16_rne(w0.y);
            bf[2] = (short)bf16_rne(w0.z); bf[3] = (short)bf16_rne(w0.w);
            bf[4] = (short)bf16_rne(w1.x); bf[5] = (short)bf16_rne(w1.y);
            bf[6] = (short)bf16_rne(w1.z); bf[7] = (short)bf16_rne(w1.w);
            bfr[nt][kt] = bf;
        }
    float as[4], at[4];
    #pragma unroll
    for (int nt = 0; nt < 4; ++nt) {
        as[nt] = a[nt * 16 + ml];
        at[nt] = a[64 + nt * 16 + ml];
    }

    for (int stripe = blockIdx.x * 4 + (threadIdx.x >> 6); stripe < nstripes;
         stripe += gridDim.x * 4) {
        const int row0 = stripe * 16;
        const int rrow = min(row0 + ml, n - 1);
        const float* xr = X + (size_t)rrow * 128;
        f32x4 acc[4] = {{0.f,0.f,0.f,0.f},{0.f,0.f,0.f,0.f},
                        {0.f,0.f,0.f,0.f},{0.f,0.f,0.f,0.f}};
        #pragma unroll
        for (int kt = 0; kt < 4; ++kt) {
            float4 x0 = *(const float4*)(xr + kt * 32 + g * 8);
            float4 x1 = *(const float4*)(xr + kt * 32 + g * 8 + 4);
            short8 af;
            af[0] = (short)bf16_rne(x0.x); af[1] = (short)bf16_rne(x0.y);
            af[2] = (short)bf16_rne(x0.z); af[3] = (short)bf16_rne(x0.w);
            af[4] = (short)bf16_rne(x1.x); af[5] = (short)bf16_rne(x1.y);
            af[6] = (short)bf16_rne(x1.z); af[7] = (short)bf16_rne(x1.w);
            #pragma unroll
            for (int nt = 0; nt < 4; ++nt)
                acc[nt] = __builtin_amdgcn_mfma_f32_16x16x32_bf16(
                    af, bfr[nt][kt], acc[nt], 0, 0, 0);
        }
        #pragma unroll
        for (int reg = 0; reg < 4; ++reg) {
            int row = row0 + g * 4 + reg;
            float p = acc[0][reg] * as[0] + acc[1][reg] * as[1] +
                      acc[2][reg] * as[2] + acc[3][reg] * as[3];
            float q = acc[0][reg] * at[0] + acc[1][reg] * at[1] +
                      acc[2][reg] * at[2] + acc[3][reg] * at[3];
            #pragma unroll
            for (int off = 1; off < 16; off <<= 1) {
                p += __shfl_xor(p, off, 64);
                q += __shfl_xor(q, off, 64);
            }
            if (ml == 0 && row < n) { s_src[row] = p; s_tgt[row] = q; }
        }
        #pragma unroll
        for (int nt = 0; nt < 4; ++nt)
            #pragma unroll
            for (int reg = 0; reg < 4; ++reg) {
                int row = row0 + g * 4 + reg;
                if (row < n)
                    hb[(size_t)row * 64 + nt * 16 + ml] = bf16_rne(acc[nt][reg]);
            }
    }
}

// ---------------------------------------------------------------------------
// k_place2: hist + alloc + place (R5 proven, unchanged).
// ---------------------------------------------------------------------------
__global__ __launch_bounds__(1024) void k_place2(
    const int* __restrict__ ei, int* __restrict__ cur,
    unsigned int* __restrict__ st, int nb, int E, int epb) {
    __shared__ int hist[NBMAX];
    __shared__ int lofs[NBMAX];
    __shared__ int gbase[NBMAX];
    __shared__ int lcur[NBMAX];
    __shared__ unsigned sorted[EPBMAX];
    __shared__ int wsum[16];
    const int t = threadIdx.x;
    const int lane = t & 63, w = t >> 6;
    const int e0 = blockIdx.x * epb, e1 = min(e0 + epb, E);
    const int cnt = e1 - e0;

    for (int k = t; k < NBMAX; k += 1024) hist[k] = 0;
    __syncthreads();

    unsigned v[4]; int nv = 0;
    for (int e = e0 + t; e < e1; e += 1024) {
        int s  = ei[e];
        int tt = ei[E + e];
        unsigned ent = (unsigned)s | ((unsigned)(tt & 63) << 16) |
                       ((unsigned)(tt >> 6) << 22);
        v[nv++] = ent;
        atomicAdd(&hist[tt >> 6], 1);
    }
    __syncthreads();

    {
        int hv = (t < nb) ? hist[t] : 0;
        int pre = hv;
        #pragma unroll
        for (int off = 1; off < 64; off <<= 1) {
            int x = __shfl_up(pre, off, 64);
            if (lane >= off) pre += x;
        }
        if (lane == 63) wsum[w] = pre;
        __syncthreads();
        int wb = 0;
        for (int k = 0; k < 16; ++k) if (k < w) wb += wsum[k];
        if (t < nb) {
            int ex = wb + pre - hv;
            lofs[t] = ex;
            lcur[t] = ex;
            if (hv > 0) gbase[t] = atomicAdd(&cur[t], hv);
        }
    }
    __syncthreads();

    for (int i = 0; i < nv; ++i) {
        unsigned ent = v[i];
        int b = ent >> 22;
        int slot = atomicAdd(&lcur[b], 1);
        sorted[slot] = ent;
    }
    __syncthreads();

    for (int i = t; i < cnt; i += 1024) {
        unsigned ent = sorted[i];
        int b = ent >> 22;
        int addr = b * CAP + gbase[b] + (i - lofs[b]);
        st[addr] = ent & 0x3FFFFFu;
    }
}

// ---------------------------------------------------------------------------
// k_local: per-bucket sort by node (R5 proven, unchanged).
// ---------------------------------------------------------------------------
__global__ __launch_bounds__(256) void k_local(
    const unsigned int* __restrict__ st, const int* __restrict__ cur,
    int* __restrict__ base, int* __restrict__ deg, int* __restrict__ csr_g,
    int n) {
    __shared__ int hist[64], lofs[64];
    __shared__ int lsorted[CAP];
    const int b = blockIdx.x;
    const int s0 = b * CAP;
    const int t = threadIdx.x;
    const int cnt = min(cur[b], CAP);
    if (t < 64) hist[t] = 0;
    __syncthreads();

    unsigned v[CAP / 256]; int nv = 0;
    for (int i = t; i < cnt; i += 256) {
        unsigned e = st[s0 + i];
        v[nv++] = e;
        atomicAdd(&hist[e >> 16], 1);
    }
    __syncthreads();
    if (t < 64) {
        int hv = hist[t];
        int pre = hv;
        #pragma unroll
        for (int off = 1; off < 64; off <<= 1) {
            int x = __shfl_up(pre, off, 64);
            if (t >= off) pre += x;
        }
        int ex = pre - hv;
        lofs[t] = ex;
        int node = (b << 6) + t;
        if (node < n) { base[node] = s0 + ex; deg[node] = hv; }
    }
    __syncthreads();
    if (t < 64) hist[t] = lofs[t];          // reuse as cursors
    __syncthreads();
    for (int i = 0; i < nv; ++i) {
        unsigned e = v[i];
        int slot = atomicAdd(&hist[e >> 16], 1);
        lsorted[slot] = (int)(e & 0xFFFFu);
    }
    __syncthreads();
    for (int i = t; i < cnt; i += 256) csr_g[s0 + i] = lsorted[i];
}

// ---------------------------------------------------------------------------
// k_node: TWO nodes per wave (one per 32-lane half) for d<=32 -- halves the
// per-node softmax/reduction/epilogue overhead, which modeled as ~2/3 of
// k_node's compute (mean d=16). shfl_xor off<=16 stays inside a half, so
// every reduction instruction serves both nodes. Gather keeps 8 row-reads
// per wave-iter (4 per node). Rare d>32 (P~1e-4) -> original 64-lane path,
// looped over the wave's 2 nodes.
// ---------------------------------------------------------------------------
__device__ __forceinline__ void accum8(float acc[8], uint4 hv, float w) {
    unsigned u[4] = {hv.x, hv.y, hv.z, hv.w};
    #pragma unroll
    for (int i = 0; i < 4; ++i) {
        float lo = __uint_as_float(u[i] << 16);
        float hi = __uint_as_float(u[i] & 0xFFFF0000u);
        acc[2 * i]     = fmaf(w, lo, acc[2 * i]);
        acc[2 * i + 1] = fmaf(w, hi, acc[2 * i + 1]);
    }
}

__global__ __launch_bounds__(256) void k_node(
    const int* __restrict__ base, const int* __restrict__ deg,
    const int* __restrict__ csr_src, const float* __restrict__ s_src,
    const float* __restrict__ s_tgt, const unsigned short* __restrict__ hb,
    float* __restrict__ out, int n) {
    const int lane = threadIdx.x & 63;
    const int pair = blockIdx.x * 4 + (threadIdx.x >> 6);   // wave id
    const int h = lane >> 5;                  // half = which node
    const int l = lane & 31;
    const int node = pair * 2 + h;
    const bool valid = node < n;

    int b = 0, d = 0; float st = 0.f;
    if (valid) { b = base[node]; d = deg[node]; st = s_tgt[node]; }
    int dmax = max(d, __shfl_xor(d, 32, 64));

    if (dmax <= 32) {
        // -------- fast path: one node per 32-lane half --------
        int src_l = 0; float w_l = 0.f, v = -INFINITY;
        if (valid && l < d) {
            src_l = csr_src[b + l];
            float x = s_src[src_l] + st;
            v = (x > 0.f) ? x : ALPHA_LEAKY * x;
        }
        float m = v;
        #pragma unroll
        for (int off = 16; off > 0; off >>= 1) m = fmaxf(m, __shfl_xor(m, off, 64));
        float ex = (valid && l < d) ? expf(v - m) : 0.f;
        float sum = ex;
        #pragma unroll
        for (int off = 16; off > 0; off >>= 1) sum += __shfl_xor(sum, off, 64);
        w_l = ex * (1.f / (sum + EPS_F));

        const int g = l >> 3, r = l & 7;      // 4 groups of 8 per half
        float acc[8] = {0.f,0.f,0.f,0.f,0.f,0.f,0.f,0.f};
        for (int k = 0; k < d; k += 4) {
            int ke = k + g;                   // <= 31 always (k<=28, g<=3)
            int s   = __shfl(src_l, (h << 5) + ke, 64);
            float w = __shfl(w_l,  (h << 5) + ke, 64);
            uint4 hv = ((const uint4*)(hb + (size_t)s * 64))[r];
            accum8(acc, hv, w);               // w==0 for ke>=d
        }
        #pragma unroll
        for (int off = 8; off <= 16; off <<= 1) {
            #pragma unroll
            for (int j = 0; j < 8; ++j) acc[j] += __shfl_xor(acc[j], off, 64);
        }
        if (g == 0 && valid) {
            float4 o0, o1;
            o0.x = acc[0] > 0.f ? acc[0] : expf(acc[0]) - 1.f;
            o0.y = acc[1] > 0.f ? acc[1] : expf(acc[1]) - 1.f;
            o0.z = acc[2] > 0.f ? acc[2] : expf(acc[2]) - 1.f;
            o0.w = acc[3] > 0.f ? acc[3] : expf(acc[3]) - 1.f;
            o1.x = acc[4] > 0.f ? acc[4] : expf(acc[4]) - 1.f;
            o1.y = acc[5] > 0.f ? acc[5] : expf(acc[5]) - 1.f;
            o1.z = acc[6] > 0.f ? acc[6] : expf(acc[6]) - 1.f;
            o1.w = acc[7] > 0.f ? acc[7] : expf(acc[7]) - 1.f;
            float4* o4 = (float4*)out + (size_t)node * 16;
            o4[r * 2]     = o0;
            o4[r * 2 + 1] = o1;
        }
        return;
    }

    // -------- slow path: full-wave per node, both nodes sequentially --------
    const int g = lane >> 3, r = lane & 7;
    for (int nn = 0; nn < 2; ++nn) {
        const int nodeX = pair * 2 + nn;
        if (nodeX >= n) continue;
        const int bb = base[nodeX];
        const int dd = deg[nodeX];
        const float stv = s_tgt[nodeX];
        float acc[8] = {0.f,0.f,0.f,0.f,0.f,0.f,0.f,0.f};

        if (dd <= 64) {
            int src_l = 0; float w_l = 0.f, v = -INFINITY;
            if (lane < dd) {
                src_l = csr_src[bb + lane];
                float x = s_src[src_l] + stv;
                v = (x > 0.f) ? x : ALPHA_LEAKY * x;
            }
            float m = v;
            #pragma unroll
            for (int off = 32; off > 0; off >>= 1) m = fmaxf(m, __shfl_xor(m, off, 64));
            float ex = (lane < dd) ? expf(v - m) : 0.f;
            float sum = ex;
            #pragma unroll
            for (int off = 32; off > 0; off >>= 1) sum += __shfl_xor(sum, off, 64);
            w_l = ex * (1.f / (sum + EPS_F));
            for (int k = 0; k < dd; k += 8) {
                int ke = k + g;
                int s   = __shfl(src_l, ke, 64);
                float w = __shfl(w_l,  ke, 64);
                uint4 hv = ((const uint4*)(hb + (size_t)s * 64))[r];
                accum8(acc, hv, w);
            }
        } else {
            float m = -INFINITY;
            for (int c = lane; c < dd; c += 64) {
                float x = s_src[csr_src[bb + c]] + stv;
                x = (x > 0.f) ? x : ALPHA_LEAKY * x;
                m = fmaxf(m, x);
            }
            #pragma unroll
            for (int off = 32; off > 0; off >>= 1) m = fmaxf(m, __shfl_xor(m, off, 64));
            float sum = 0.f;
            for (int c = lane; c < dd; c += 64) {
                float x = s_src[csr_src[bb + c]] + stv;
                x = (x > 0.f) ? x : ALPHA_LEAKY * x;
                sum += expf(x - m);
            }
            #pragma unroll
            for (int off = 32; off > 0; off >>= 1) sum += __shfl_xor(sum, off, 64);
            float inv = 1.f / (sum + EPS_F);
            for (int c0 = 0; c0 < dd; c0 += 64) {
                int j = c0 + lane;
                int src_l = 0; float w_l = 0.f;
                if (j < dd) {
                    src_l = csr_src[bb + j];
                    float x = s_src[src_l] + stv;
                    x = (x > 0.f) ? x : ALPHA_LEAKY * x;
                    w_l = expf(x - m) * inv;
                }
                int lim = min(64, dd - c0);
                for (int k = 0; k < lim; k += 8) {
                    int ke = k + g;
                    int s   = __shfl(src_l, ke, 64);
                    float w = __shfl(w_l,  ke, 64);
                    uint4 hv = ((const uint4*)(hb + (size_t)s * 64))[r];
                    accum8(acc, hv, w);
                }
            }
        }

        #pragma unroll
        for (int off = 8; off <= 32; off <<= 1) {
            #pragma unroll
            for (int j = 0; j < 8; ++j) acc[j] += __shfl_xor(acc[j], off, 64);
        }
        if (g == 0) {
            float4 o0, o1;
            o0.x = acc[0] > 0.f ? acc[0] : expf(acc[0]) - 1.f;
            o0.y = acc[1] > 0.f ? acc[1] : expf(acc[1]) - 1.f;
            o0.z = acc[2] > 0.f ? acc[2] : expf(acc[2]) - 1.f;
            o0.w = acc[3] > 0.f ? acc[3] : expf(acc[3]) - 1.f;
            o1.x = acc[4] > 0.f ? acc[4] : expf(acc[4]) - 1.f;
            o1.y = acc[5] > 0.f ? acc[5] : expf(acc[5]) - 1.f;
            o1.z = acc[6] > 0.f ? acc[6] : expf(acc[6]) - 1.f;
            o1.w = acc[7] > 0.f ? acc[7] : expf(acc[7]) - 1.f;
            float4* o4 = (float4*)out + (size_t)nodeX * 16;
            o4[r * 2]     = o0;
            o4[r * 2 + 1] = o1;
        }
    }
}

extern "C" void kernel_launch(void* const* d_in, const int* in_sizes, int n_in,
                              void* d_out, int out_size, void* d_ws, size_t ws_size,
                              hipStream_t stream) {
    const float* X  = (const float*)d_in[0];   // [N,128]
    const int*   ei = (const int*)d_in[1];     // [2,E]
    const float* W  = (const float*)d_in[2];   // [64,128]
    const float* a  = (const float*)d_in[3];   // [1,128]
    float* out = (float*)d_out;                // [N,64]

    const int N = in_sizes[0] / 128;
    const int E = in_sizes[1] / 2;
    const int nb = (N + 63) >> 6;              // buckets of 64 nodes (<=1024)
    const int nstripes = (N + 15) / 16;
    const int Rg = (nstripes + 3) / 4;         // gemm grid
    const int epb = (E + PLACE_BLOCKS - 1) / PLACE_BLOCKS;

    char* p = (char*)d_ws;
    unsigned short* hb = (unsigned short*)p; p += (size_t)N * 64 * sizeof(unsigned short);
    float* s_src  = (float*)p;  p += (size_t)N * sizeof(float);
    float* s_tgt  = (float*)p;  p += (size_t)N * sizeof(float);
    int*   deg    = (int*)p;    p += (size_t)N * sizeof(int);
    int*   base   = (int*)p;    p += (size_t)N * sizeof(int);
    int*   cur    = (int*)p;    p += (size_t)NBMAX * sizeof(int);
    unsigned int* st = (unsigned int*)p; p += (size_t)nb * CAP * sizeof(unsigned int);
    int*   csr_g  = (int*)p;

    k_gemm  <<<Rg, 256, 0, stream>>>(X, W, a, hb, s_src, s_tgt, cur, nb, N, nstripes);
    k_place2<<<PLACE_BLOCKS, 1024, 0, stream>>>(ei, cur, st, nb, E, epb);
    k_local <<<nb, 256, 0, stream>>>(st, cur, base, deg, csr_g, N);
    k_node  <<<(N + 7) / 8, 256, 0, stream>>>(base, deg, csr_g, s_src, s_tgt,
                                              hb, out, N);
}